// Round 1
// baseline (1004.967 us; speedup 1.0000x reference)
//
#include <hip/hip_runtime.h>
#include <hip/hip_bf16.h>

// ConstitutiveModel: B=2048 samples, T=64 sequential steps, H=128, NIV=10.
// One wave per sample (lane owns hidden units 2l, 2l+1). 8 waves/block,
// 256 blocks = 1 block/CU. Weights in LDS (loaded once); activations stay
// in registers, broadcast via v_readlane. No barriers inside the t-loop.

#define NIV 10
#define DT_C 0.01f

__device__ __forceinline__ float bcast(float v, int l) {
    return __int_as_float(__builtin_amdgcn_readlane(__float_as_int(v), l));
}

__global__ __launch_bounds__(512, 2) void cm_kernel(
    const float* __restrict__ eps,
    const float* __restrict__ gwW1, const float* __restrict__ gwb1,
    const float* __restrict__ gwW2, const float* __restrict__ gwb2,
    const float* __restrict__ gwW3,
    const float* __restrict__ gdW1, const float* __restrict__ gdb1,
    const float* __restrict__ gdW2, const float* __restrict__ gdb2,
    const float* __restrict__ gdWc,
    float* __restrict__ out)
{
    // --- LDS: 40448 floats = 161792 B (gfx950 max 163840) ---
    __shared__ __align__(16) float sW2[16384];   // swizzled: (r,c) at r*128 + 2*((c>>1)^(r>>1)) + (c&1)
    __shared__ __align__(16) float sD2[16384];   // same swizzle
    __shared__ __align__(16) float sW1[2048];    // [16][128] row-major
    __shared__ __align__(16) float sW1T[2048];   // [128][16]: sW1T[r*16+k] = wW1[k][r]
    __shared__ __align__(16) float sD1[1280];    // [10][128] row-major
    __shared__ __align__(16) float sD1T[1536];   // [128][12] padded: sD1T[r*12+m] = dW1[m][r]
    __shared__ float sb1[128], sb2[128], sW3[128], sdb1[128], sdb2[128], sDc2[128];

    const int tid = threadIdx.x;

    for (int i = tid; i < 16384; i += 512) {
        int r = i >> 7, c = i & 127;
        int idx = (r << 7) + ((((c >> 1) ^ (r >> 1)) & 63) << 1) + (c & 1);
        sW2[idx] = gwW2[i];
        sD2[idx] = gdW2[i];
    }
    for (int i = tid; i < 2048; i += 512) {
        sW1[i] = gwW1[i];
        int k = i >> 7, r = i & 127;
        sW1T[r * 16 + k] = gwW1[i];
    }
    for (int i = tid; i < 1280; i += 512) sD1[i] = gdW1[i];
    for (int i = tid; i < 1536; i += 512) {
        int r = i / 12, m = i - r * 12;
        sD1T[i] = (m < 10) ? gdW1[m * 128 + r] : 0.f;
    }
    if (tid < 128) {
        sb1[tid]  = gwb1[tid];
        sb2[tid]  = gwb2[tid];
        sW3[tid]  = gwW3[tid];
        sdb1[tid] = gdb1[tid];
        sdb2[tid] = gdb2[tid];
        float w = gdWc[tid];
        sDc2[tid] = w * w;                 // ConvexLayer: squared weights
    }
    __syncthreads();                       // only barrier in the kernel

    const int lane = tid & 63;
    const int wv   = tid >> 6;
    const int b    = blockIdx.x * 8 + wv;  // grid 256 * 8 waves = 2048 samples
    const int c0   = lane * 2, c1 = lane * 2 + 1;
    const int k16  = lane & 15;
    const int k12  = (k16 < 12) ? k16 : 0; // clamp: avoid OOB in padded sD1T

    float xi[NIV];
#pragma unroll
    for (int m = 0; m < NIV; ++m) xi[m] = 0.f;

    const float* ep = eps + b * (64 * 6);
    float*       op = out + b * (64 * 6);

    for (int t = 0; t < 64; ++t) {
        // x0 = [e - eye, xi], eye = [1,0,0,1,0,1]
        float x0[16];
        x0[0] = ep[t*6+0] - 1.f; x0[1] = ep[t*6+1];       x0[2] = ep[t*6+2];
        x0[3] = ep[t*6+3] - 1.f; x0[4] = ep[t*6+4];       x0[5] = ep[t*6+5] - 1.f;
#pragma unroll
        for (int m = 0; m < NIV; ++m) x0[6+m] = xi[m];

        // ---- free energy forward: z1 = x0 @ wW1 + b1 ----
        float z1a = sb1[c0], z1b = sb1[c1];
#pragma unroll
        for (int k = 0; k < 16; ++k) {
            z1a = fmaf(x0[k], sW1[k*128 + c0], z1a);
            z1b = fmaf(x0[k], sW1[k*128 + c1], z1b);
        }
        float r1a = fmaxf(z1a, 0.f), r1b = fmaxf(z1b, 0.f);
        float a1a = r1a * r1a,       a1b = r1b * r1b;

        // ---- z2 = a1 @ wW2 + b2 (fwd column access, swizzled b64) ----
        float z2a = sb2[c0], z2b = sb2[c1];
#pragma unroll 16
        for (int j = 0; j < 64; ++j) {
            float v0 = bcast(a1a, j), v1 = bcast(a1b, j);   // a1[2j], a1[2j+1]
            int o = (lane ^ j) << 1;
            const float2 w0 = *(const float2*)(sW2 + (j << 8) + o);        // row 2j,  cols c0,c1
            const float2 w1 = *(const float2*)(sW2 + (j << 8) + 128 + o);  // row 2j+1
            z2a = fmaf(v0, w0.x, z2a); z2a = fmaf(v1, w1.x, z2a);
            z2b = fmaf(v0, w0.y, z2b); z2b = fmaf(v1, w1.y, z2b);
        }
        float r2a = fmaxf(z2a, 0.f), r2b = fmaxf(z2b, 0.f);
        // gz2 = dW/dz2 = wW3 * 2*relu(z2)
        float gza = 2.f * r2a * sW3[c0], gzb = 2.f * r2b * sW3[c1];

        // ---- g1[r] = sum_c wW2[r][c] * gz2[c] (bwd row access) ----
        float g1a = 0.f, g1b = 0.f;
#pragma unroll 16
        for (int j = 0; j < 64; ++j) {
            float v0 = bcast(gza, j), v1 = bcast(gzb, j);   // gz2[2j], gz2[2j+1]
            int o = (lane ^ j) << 1;
            const float2 wa = *(const float2*)(sW2 + c0*128 + o);   // row c0, cols 2j,2j+1
            const float2 wb = *(const float2*)(sW2 + c1*128 + o);
            g1a = fmaf(wa.x, v0, g1a); g1a = fmaf(wa.y, v1, g1a);
            g1b = fmaf(wb.x, v0, g1b); g1b = fmaf(wb.y, v1, g1b);
        }
        float gz1a = 2.f * g1a * r1a, gz1b = 2.f * g1b * r1b;

        // ---- gx0[k] = sum_r gz1[r] * wW1[k][r], lane computes k = lane&15 ----
        float gx = 0.f;
#pragma unroll 16
        for (int j = 0; j < 64; ++j) {
            float v0 = bcast(gz1a, j), v1 = bcast(gz1b, j);
            gx = fmaf(v0, sW1T[(j << 5) + k16],      gx);
            gx = fmaf(v1, sW1T[(j << 5) + 16 + k16], gx);
        }
        // stress = gx0[0:6]
        if (lane < 6) op[t*6 + lane] = gx;

        // d = -gx0[6:16]
        float dm[NIV];
#pragma unroll
        for (int m = 0; m < NIV; ++m) dm[m] = -bcast(gx, 6 + m);

        // ---- dissipation forward: u1 = d @ dW1 + db1 ----
        float u1a = sdb1[c0], u1b = sdb1[c1];
#pragma unroll
        for (int m = 0; m < NIV; ++m) {
            u1a = fmaf(dm[m], sD1[m*128 + c0], u1a);
            u1b = fmaf(dm[m], sD1[m*128 + c1], u1b);
        }
        float p1a = fmaxf(u1a, 0.f), p1b = fmaxf(u1b, 0.f);
        float q1a = p1a * p1a,       q1b = p1b * p1b;

        // ---- u2 = b1 @ dW2 + db2 ----
        float u2a = sdb2[c0], u2b = sdb2[c1];
#pragma unroll 16
        for (int j = 0; j < 64; ++j) {
            float v0 = bcast(q1a, j), v1 = bcast(q1b, j);
            int o = (lane ^ j) << 1;
            const float2 w0 = *(const float2*)(sD2 + (j << 8) + o);
            const float2 w1 = *(const float2*)(sD2 + (j << 8) + 128 + o);
            u2a = fmaf(v0, w0.x, u2a); u2a = fmaf(v1, w1.x, u2a);
            u2b = fmaf(v0, w0.y, u2b); u2b = fmaf(v1, w1.y, u2b);
        }
        // hu2 = dWc^2 * 2*relu(u2)
        float hu2a = 2.f * fmaxf(u2a, 0.f) * sDc2[c0];
        float hu2b = 2.f * fmaxf(u2b, 0.f) * sDc2[c1];

        // ---- h1[r] = sum_c dW2[r][c] * hu2[c] ----
        float h1a = 0.f, h1b = 0.f;
#pragma unroll 16
        for (int j = 0; j < 64; ++j) {
            float v0 = bcast(hu2a, j), v1 = bcast(hu2b, j);
            int o = (lane ^ j) << 1;
            const float2 wa = *(const float2*)(sD2 + c0*128 + o);
            const float2 wb = *(const float2*)(sD2 + c1*128 + o);
            h1a = fmaf(wa.x, v0, h1a); h1a = fmaf(wa.y, v1, h1a);
            h1b = fmaf(wb.x, v0, h1b); h1b = fmaf(wb.y, v1, h1b);
        }
        float hu1a = 2.f * h1a * p1a, hu1b = 2.f * h1b * p1b;

        // ---- gd[m] = sum_r dW1[m][r] * hu1[r], lane computes m = k12 ----
        float gd = 0.f;
#pragma unroll 16
        for (int j = 0; j < 64; ++j) {
            float v0 = bcast(hu1a, j), v1 = bcast(hu1b, j);
            gd = fmaf(v0, sD1T[j*24 + k12],      gd);
            gd = fmaf(v1, sD1T[j*24 + 12 + k12], gd);
        }

        // xi += DT * gd
#pragma unroll
        for (int m = 0; m < NIV; ++m) xi[m] = fmaf(DT_C, bcast(gd, m), xi[m]);
    }
}

extern "C" void kernel_launch(void* const* d_in, const int* in_sizes, int n_in,
                              void* d_out, int out_size, void* d_ws, size_t ws_size,
                              hipStream_t stream) {
    const float* eps = (const float*)d_in[0];
    const float* wW1 = (const float*)d_in[1];
    const float* wb1 = (const float*)d_in[2];
    const float* wW2 = (const float*)d_in[3];
    const float* wb2 = (const float*)d_in[4];
    const float* wW3 = (const float*)d_in[5];
    // d_in[6] = wb3: constant offset, vanishes in the gradient — unused.
    const float* dW1 = (const float*)d_in[7];
    const float* db1 = (const float*)d_in[8];
    const float* dW2 = (const float*)d_in[9];
    const float* db2 = (const float*)d_in[10];
    const float* dWc = (const float*)d_in[11];
    float* out = (float*)d_out;

    cm_kernel<<<dim3(256), dim3(512), 0, stream>>>(
        eps, wW1, wb1, wW2, wb2, wW3, dW1, db1, dW2, db2, dWc, out);
}